// Round 7
// baseline (3526.044 us; speedup 1.0000x reference)
//
#include <hip/hip_runtime.h>
#include <math.h>

// ---------------------------------------------------------------------------
// ConvLSTM stack: 4 x (ConvLSTM2D + MaxPool(1,2,2)) -> Flatten -> Dense -> Softmax
// Channels-last (B,T,H,W,C) contiguous everywhere (matches ref).
//
// Round-7: LAYER-PIPELINED slots. Layer L step t depends only on layer L-1
// step t, so slot s runs concurrently (as block-ranges of ONE kernel):
//   L1 step s | pool1(s-1) | L2 step s-2 | pool2(s-3) | L3 step s-4
//   | pool3(s-5) | L4 step s-6 | pool4(s-7)
// All intra-slot phases touch disjoint data; every producer->consumer edge
// crosses a dispatch boundary (stream-ordered). 31 slots + 2 dense = 33
// dispatches (was 101). Tail layers (L3/L4: 421/85 blocks) now co-run with
// L1/L2's ~2800 blocks instead of idling 256 CUs.
//
// Per-phase algorithms = round-6 best: L1 merged-gates 2px/thread; L2/L3/L4
// gate-split waves (wave = gate -> weights wave-uniform SGPR); pools 4 items
// per thread. fast tanh via v_exp/v_rcp (|err|~1e-6).
// ---------------------------------------------------------------------------

static __device__ __forceinline__ float hsig(float x) {
    return fminf(fmaxf(fmaf(0.2f, x, 0.5f), 0.0f), 1.0f);
}
static __device__ __forceinline__ float ftanh(float x) {
    float e = __builtin_amdgcn_exp2f(x * 2.88539008177792681f);
    return 1.0f - 2.0f * __builtin_amdgcn_rcpf(e + 1.0f);
}

// ---- L1: merged gates, two adjacent pixels (same row) per thread ----
template<int CIN, int F, int HIN, int WIN>
static __device__ void step_pair_dev(
    const float* __restrict__ P, const float* __restrict__ Wx,
    const float* __restrict__ Wh, const float* __restrict__ bias,
    float* __restrict__ hs, float* __restrict__ cbuf, int t, int bid, int tid)
{
    constexpr int B = 32, T = 24, HO = HIN - 2, WO = WIN - 2, G = 4 * F;
    constexpr int XP = WO / 2;
    constexpr int NPAIR = B * HO * XP;
    const int id = bid * 256 + tid;
    if (id >= NPAIR) return;
    const int xp = id % XP;
    const int yy = (id / XP) % HO;
    const int b  = id / (XP * HO);
    const int x0 = 2 * xp;

    float acc[2][4][F];
    #pragma unroll
    for (int u = 0; u < 2; ++u)
        #pragma unroll
        for (int g = 0; g < 4; ++g)
            #pragma unroll
            for (int f = 0; f < F; ++f)
                acc[u][g][f] = bias[g * F + f];

    const float* Pt = P + (size_t)(b * T + t) * HIN * WIN * CIN;
    #pragma unroll
    for (int ky = 0; ky < 3; ++ky) {
        const float* prow = Pt + ((size_t)(yy + ky) * WIN + x0) * CIN;
        float pv[4 * CIN];
        #pragma unroll
        for (int j = 0; j < 2 * CIN; ++j) {
            float2 v2 = reinterpret_cast<const float2*>(prow)[j];
            pv[2 * j] = v2.x; pv[2 * j + 1] = v2.y;
        }
        #pragma unroll
        for (int dx = 0; dx < 4; ++dx)
            #pragma unroll
            for (int ci = 0; ci < CIN; ++ci) {
                const float v = pv[dx * CIN + ci];
                #pragma unroll
                for (int u = 0; u < 2; ++u) {
                    const int kx = dx - u;
                    if (kx >= 0 && kx <= 2) {
                        const float* wr = Wx + (size_t)((ky * 3 + kx) * CIN + ci) * G;
                        #pragma unroll
                        for (int g = 0; g < 4; ++g)
                            #pragma unroll
                            for (int f = 0; f < F; ++f)
                                acc[u][g][f] = fmaf(v, wr[g * F + f], acc[u][g][f]);
                    }
                }
            }
    }

    if (t > 0) {
        const float* Hp = hs + (size_t)(b * T + (t - 1)) * HO * WO * F;
        #pragma unroll
        for (int ky = 0; ky < 3; ++ky) {
            const int hy = yy + ky - 1;
            if (hy < 0 || hy >= HO) continue;
            const float* hrow = Hp + (size_t)hy * WO * F;
            #pragma unroll
            for (int dx = 0; dx < 4; ++dx) {
                const int hx = x0 - 1 + dx;
                if (dx == 0 && x0 == 0) continue;
                if (dx == 3 && hx >= WO) continue;
                const float4* h4 =
                    reinterpret_cast<const float4*>(hrow + (size_t)hx * F);
                float hv[F];
                #pragma unroll
                for (int j = 0; j < F / 4; ++j) {
                    float4 v4 = h4[j];
                    hv[4*j] = v4.x; hv[4*j+1] = v4.y;
                    hv[4*j+2] = v4.z; hv[4*j+3] = v4.w;
                }
                #pragma unroll
                for (int ci = 0; ci < F; ++ci) {
                    const float v = hv[ci];
                    #pragma unroll
                    for (int u = 0; u < 2; ++u) {
                        const int kx = dx - u;
                        if (kx >= 0 && kx <= 2) {
                            const float* wr = Wh + (size_t)((ky * 3 + kx) * F + ci) * G;
                            #pragma unroll
                            for (int g = 0; g < 4; ++g)
                                #pragma unroll
                                for (int f = 0; f < F; ++f)
                                    acc[u][g][f] = fmaf(v, wr[g * F + f], acc[u][g][f]);
                        }
                    }
                }
            }
        }
    }

    #pragma unroll
    for (int u = 0; u < 2; ++u) {
        const size_t pix = ((size_t)b * HO + yy) * WO + (x0 + u);
        float cn[F], ho[F];
        float* cp = cbuf + pix * F;
        #pragma unroll
        for (int j = 0; j < F / 4; ++j) {
            float4 c4 = (t > 0) ? reinterpret_cast<float4*>(cp)[j]
                                : make_float4(0.f, 0.f, 0.f, 0.f);
            float cold[4] = {c4.x, c4.y, c4.z, c4.w};
            #pragma unroll
            for (int v = 0; v < 4; ++v) {
                const int f = 4 * j + v;
                const float ig = hsig(acc[u][0][f]), fg = hsig(acc[u][1][f]);
                const float cc = ftanh(acc[u][2][f]), og = hsig(acc[u][3][f]);
                cn[f] = fmaf(fg, cold[v], ig * cc);
                ho[f] = og * ftanh(cn[f]);
            }
            reinterpret_cast<float4*>(cp)[j] =
                make_float4(cn[4*j], cn[4*j+1], cn[4*j+2], cn[4*j+3]);
        }
        float* hp = hs + ((size_t)(b * T + t) * HO * WO
                          + (size_t)yy * WO + (x0 + u)) * F;
        #pragma unroll
        for (int j = 0; j < F / 4; ++j)
            reinterpret_cast<float4*>(hp)[j] =
                make_float4(ho[4*j], ho[4*j+1], ho[4*j+2], ho[4*j+3]);
    }
}

// ---- gate-split step (L2/L3/L4): wave w = gate w of 64 pixels ----
// gb = 4 rows of 1024 floats (kernel-scope LDS union).
template<int CIN, int F, int HIN, int WIN>
static __device__ void step_split_dev(
    const float* __restrict__ P, const float* __restrict__ Wx,
    const float* __restrict__ Wh, const float* __restrict__ bias,
    float* __restrict__ hs, float* __restrict__ cbuf, int t, int bid, int tid,
    float* __restrict__ gb)
{
    constexpr int B = 32, T = 24, HO = HIN - 2, WO = WIN - 2, G = 4 * F;
    constexpr int NPIX = B * HO * WO;
    const int lane = tid & 63;
    const int w = __builtin_amdgcn_readfirstlane(tid >> 6);
    const int pix = bid * 64 + lane;
    const int pp  = (pix < NPIX) ? pix : NPIX - 1;
    const int s   = pp % (HO * WO);
    const int b   = pp / (HO * WO);
    const int xx  = s % WO, yy = s / WO;

    float acc[F];
    #pragma unroll
    for (int f = 0; f < F; ++f) acc[f] = bias[w * F + f];

    const float* Pt = P + (size_t)(b * T + t) * HIN * WIN * CIN;
    #pragma unroll
    for (int ky = 0; ky < 3; ++ky) {
        #pragma unroll
        for (int kx = 0; kx < 3; ++kx) {
            const float* prow = Pt + ((size_t)(yy + ky) * WIN + (xx + kx)) * CIN;
            float pv[CIN];
            #pragma unroll
            for (int j = 0; j < CIN / 4; ++j) {
                float4 v4 = reinterpret_cast<const float4*>(prow)[j];
                pv[4*j] = v4.x; pv[4*j+1] = v4.y; pv[4*j+2] = v4.z; pv[4*j+3] = v4.w;
            }
            #pragma unroll
            for (int ci = 0; ci < CIN; ++ci) {
                const float v = pv[ci];
                const float* wr = Wx + (size_t)((ky * 3 + kx) * CIN + ci) * G + w * F;
                #pragma unroll
                for (int f = 0; f < F; ++f)
                    acc[f] = fmaf(v, wr[f], acc[f]);
            }
        }
    }

    if (t > 0) {
        const float* Hp = hs + (size_t)(b * T + (t - 1)) * HO * WO * F;
        #pragma unroll
        for (int ky = 0; ky < 3; ++ky) {
            const int hy = yy + ky - 1;
            if (hy < 0 || hy >= HO) continue;
            #pragma unroll
            for (int kx = 0; kx < 3; ++kx) {
                const int hx = xx + kx - 1;
                if (hx < 0 || hx >= WO) continue;
                const float4* h4 = reinterpret_cast<const float4*>(
                    Hp + ((size_t)hy * WO + hx) * F);
                float hv[F];
                #pragma unroll
                for (int j = 0; j < F / 4; ++j) {
                    float4 v4 = h4[j];
                    hv[4*j] = v4.x; hv[4*j+1] = v4.y; hv[4*j+2] = v4.z; hv[4*j+3] = v4.w;
                }
                #pragma unroll
                for (int ci = 0; ci < F; ++ci) {
                    const float v = hv[ci];
                    const float* wr = Wh + (size_t)((ky * 3 + kx) * F + ci) * G + w * F;
                    #pragma unroll
                    for (int f = 0; f < F; ++f)
                        acc[f] = fmaf(v, wr[f], acc[f]);
                }
            }
        }
    }

    #pragma unroll
    for (int f = 0; f < F; ++f) gb[w * 1024 + lane * F + f] = acc[f];
    __syncthreads();

    #pragma unroll
    for (int r = 0; r < F / 4; ++r) {
        const int it = r * 256 + tid;
        const int pl = it / F, fo = it % F;
        const int pix2 = bid * 64 + pl;
        if (pix2 < NPIX) {
            const float ig = hsig(gb[0 * 1024 + it]), fg = hsig(gb[1 * 1024 + it]);
            const float cc = ftanh(gb[2 * 1024 + it]), og = hsig(gb[3 * 1024 + it]);
            const size_t cix = (size_t)pix2 * F + fo;
            const float cold = (t > 0) ? cbuf[cix] : 0.0f;
            const float cnw = fmaf(fg, cold, ig * cc);
            cbuf[cix] = cnw;
            const int s2 = pix2 % (HO * WO);
            const int b2 = pix2 / (HO * WO);
            hs[((size_t)(b2 * T + t) * HO * WO + s2) * F + fo] = og * ftanh(cnw);
        }
    }
}

// ---- MaxPool(2,2) SAME for one timestep; 4 consecutive items/thread ----
template<int F, int HO, int WO, int HP, int WP>
static __device__ void pool_dev(const float* __restrict__ hfull,  // (B,T,HO,WO,F)
                                float* __restrict__ pooled,       // (B,T,HP,WP,F)
                                int tt, int bid, int tid)
{
    constexpr int B = 32, T = 24;
    constexpr int NP = B * HP * WP * F;
    const int i0 = (bid * 256 + tid) * 4;
    #pragma unroll
    for (int u = 0; u < 4; ++u) {
        const int i = i0 + u;
        if (i >= NP) return;
        const int f  = i % F;
        const int xo = (i / F) % WP;
        const int yo = (i / (F * WP)) % HP;
        const int b  = i / (F * WP * HP);
        const int y0 = 2 * yo, x0 = 2 * xo;
        const float* base =
            hfull + ((size_t)(b * T + tt) * HO * WO + (size_t)y0 * WO + x0) * F + f;
        float m = base[0];
        if (x0 + 1 < WO) m = fmaxf(m, base[F]);
        if (y0 + 1 < HO) {
            m = fmaxf(m, base[(size_t)WO * F]);
            if (x0 + 1 < WO) m = fmaxf(m, base[(size_t)WO * F + F]);
        }
        pooled[((size_t)(b * T + tt) * HP * WP + (size_t)yo * WP + xo) * F + f] = m;
    }
}

// ---- pipelined slot mega-kernel ----
// block ranges: [0,993) L1 | [993,1490) pool1 | [1490,3351) L2 |
// [3351,3592) pool2 | [3592,4013) L3 | [4013,4098) pool3 |
// [4098,4183) L4 | [4183,4208) pool4
__global__ __launch_bounds__(256)
void slot_k(const float* __restrict__ x,
            const float* __restrict__ Wx1, const float* __restrict__ Wh1,
            const float* __restrict__ b1,
            const float* __restrict__ Wx2, const float* __restrict__ Wh2,
            const float* __restrict__ b2,
            const float* __restrict__ Wx3, const float* __restrict__ Wh3,
            const float* __restrict__ b3,
            const float* __restrict__ Wx4, const float* __restrict__ Wh4,
            const float* __restrict__ b4,
            float* h1, float* c1, float* p1,
            float* h2, float* c2, float* p2,
            float* h3, float* c3, float* p3,
            float* h4, float* c4, float* p4,
            int s)
{
    __shared__ float gb[4 * 1024];
    const int tid = threadIdx.x;
    int bid = blockIdx.x;

    if (bid < 993) {                                   // L1 step t=s
        if (s < 24) step_pair_dev<3, 4, 128, 128>(x, Wx1, Wh1, b1, h1, c1, s, bid, tid);
        return;
    }
    bid -= 993;
    if (bid < 497) {                                   // pool1 t=s-1
        const int t = s - 1;
        if (t >= 0 && t < 24) pool_dev<4, 126, 126, 63, 63>(h1, p1, t, bid, tid);
        return;
    }
    bid -= 497;
    if (bid < 1861) {                                  // L2 step t=s-2
        const int t = s - 2;
        if (t >= 0 && t < 24)
            step_split_dev<4, 8, 63, 63>(p1, Wx2, Wh2, b2, h2, c2, t, bid, tid, gb);
        return;
    }
    bid -= 1861;
    if (bid < 241) {                                   // pool2 t=s-3
        const int t = s - 3;
        if (t >= 0 && t < 24) pool_dev<8, 61, 61, 31, 31>(h2, p2, t, bid, tid);
        return;
    }
    bid -= 241;
    if (bid < 421) {                                   // L3 step t=s-4
        const int t = s - 4;
        if (t >= 0 && t < 24)
            step_split_dev<8, 12, 31, 31>(p2, Wx3, Wh3, b3, h3, c3, t, bid, tid, gb);
        return;
    }
    bid -= 421;
    if (bid < 85) {                                    // pool3 t=s-5
        const int t = s - 5;
        if (t >= 0 && t < 24) pool_dev<12, 29, 29, 15, 15>(h3, p3, t, bid, tid);
        return;
    }
    bid -= 85;
    if (bid < 85) {                                    // L4 step t=s-6
        const int t = s - 6;
        if (t >= 0 && t < 24)
            step_split_dev<12, 16, 15, 15>(p3, Wx4, Wh4, b4, h4, c4, t, bid, tid, gb);
        return;
    }
    bid -= 85;
    {                                                  // pool4 t=s-7
        const int t = s - 7;
        if (t >= 0 && t < 24) pool_dev<16, 13, 13, 7, 7>(h4, p4, t, bid, tid);
    }
}

// ---- Dense (18816 x 50) stage 1: partial sums over FLAT chunks ----
__global__ __launch_bounds__(256)
void dense_partial_k(const float* __restrict__ X, const float* __restrict__ Wd,
                     float* __restrict__ part)
{
    constexpr int FLAT = 18816, K = 50, NC = 12, CHUNK = FLAT / NC; // 1568
    const int b = blockIdx.x, ch = blockIdx.y;
    const int tid = threadIdx.x, lane = tid & 63, wv = tid >> 6;
    const float* x = X + (size_t)b * FLAT;
    const int i0 = ch * CHUNK + wv * (CHUNK / 4);
    float a0 = 0.f, a1 = 0.f, a2 = 0.f, a3 = 0.f;
    if (lane < K) {
        for (int i = i0; i < i0 + CHUNK / 4; i += 4) {
            a0 = fmaf(x[i + 0], Wd[(size_t)(i + 0) * K + lane], a0);
            a1 = fmaf(x[i + 1], Wd[(size_t)(i + 1) * K + lane], a1);
            a2 = fmaf(x[i + 2], Wd[(size_t)(i + 2) * K + lane], a2);
            a3 = fmaf(x[i + 3], Wd[(size_t)(i + 3) * K + lane], a3);
        }
    }
    __shared__ float red[256];
    red[tid] = (a0 + a1) + (a2 + a3);
    __syncthreads();
    if (tid < 64 && lane < K)
        part[((size_t)b * NC + ch) * K + lane]
            = red[tid] + red[tid + 64] + red[tid + 128] + red[tid + 192];
}

__global__ __launch_bounds__(64)
void dense_finish_k(const float* __restrict__ part, const float* __restrict__ bd,
                    float* __restrict__ out)
{
    constexpr int K = 50, NC = 12;
    const int b = blockIdx.x, lane = threadIdx.x;
    float v = -INFINITY;
    if (lane < K) {
        v = bd[lane];
        #pragma unroll
        for (int c = 0; c < NC; ++c)
            v += part[((size_t)b * NC + c) * K + lane];
    }
    float m = v;
    #pragma unroll
    for (int off = 32; off > 0; off >>= 1) m = fmaxf(m, __shfl_xor(m, off));
    float e = (lane < K) ? __expf(v - m) : 0.0f;
    float s = e;
    #pragma unroll
    for (int off = 32; off > 0; off >>= 1) s += __shfl_xor(s, off);
    if (lane < K) out[(size_t)b * K + lane] = e / s;
}

extern "C" void kernel_launch(void* const* d_in, const int* in_sizes, int n_in,
                              void* d_out, int out_size, void* d_ws, size_t ws_size,
                              hipStream_t stream)
{
    const float* x   = (const float*)d_in[0];
    const float* Wx1 = (const float*)d_in[1];
    const float* Wh1 = (const float*)d_in[2];
    const float* b1  = (const float*)d_in[3];
    const float* Wx2 = (const float*)d_in[4];
    const float* Wh2 = (const float*)d_in[5];
    const float* b2  = (const float*)d_in[6];
    const float* Wx3 = (const float*)d_in[7];
    const float* Wh3 = (const float*)d_in[8];
    const float* b3  = (const float*)d_in[9];
    const float* Wx4 = (const float*)d_in[10];
    const float* Wh4 = (const float*)d_in[11];
    const float* b4  = (const float*)d_in[12];
    const float* Wd  = (const float*)d_in[13];
    const float* bd  = (const float*)d_in[14];
    float* out = (float*)d_out;

    // ---- workspace (floats): 105,646,464 total = 422.6 MB < ws_size ----
    float* ws = (float*)d_ws;
    float* h1 = ws;                     // 768*126*126*4 = 48,771,072
    float* p1 = ws + 48771072;          // 768*63*63*4   = 12,192,768
    float* h2 = ws + 60963840;          // 768*61*61*8   = 22,861,824
    float* p2 = ws + 83825664;          // 768*31*31*8   =  5,904,384
    float* h3 = ws + 89730048;          // 768*29*29*12  =  7,750,656
    float* p3 = ws + 97480704;          // 768*15*15*12  =  2,073,600
    float* h4 = ws + 99554304;          // 768*13*13*16  =  2,076,672
    float* p4 = ws + 101630976;         // 768*7*7*16    =    602,112
    float* c1 = ws + 102233088;         // 32*126*126*4  =  2,032,128
    float* c2 = ws + 104265216;         // 32*61*61*8    =    952,576
    float* c3 = ws + 105217792;         // 32*29*29*12   =    322,944
    float* c4 = ws + 105540736;         // 32*13*13*16   =     86,528
    float* dpart = ws + 105627264;      // 32*12*50      =     19,200

    // 31 pipelined slots
    for (int s = 0; s < 31; ++s)
        slot_k<<<4208, 256, 0, stream>>>(
            x, Wx1, Wh1, b1, Wx2, Wh2, b2, Wx3, Wh3, b3, Wx4, Wh4, b4,
            h1, c1, p1, h2, c2, p2, h3, c3, p3, h4, c4, p4, s);

    // p4 = (B, 18816) row-major == Keras Flatten
    dense_partial_k<<<dim3(32, 12), 256, 0, stream>>>(p4, Wd, dpart);
    dense_finish_k<<<32, 64, 0, stream>>>(dpart, bd, out);
}